// Round 13
// baseline (155.480 us; speedup 1.0000x reference)
//
#include <hip/hip_runtime.h>
#include <hip/hip_bf16.h>

typedef int int4v __attribute__((ext_vector_type(4)));

#define K_DIM 2048
#define N_DIM 2048
#define M_DIM 16384
#define NW 4194304   // weight element count (2048*2048)
#define BKB 128      // K-step bytes per row (128 i8 elements)
#define NKT (K_DIM / BKB)   // 16 K-tiles

// ------------- fused: per-token absmax+quant, plus wsum slice (blocks<256) ---
__device__ __forceinline__ char qi8(float v, double rr) {
  double q = rint((double)v * rr);
  q = fmin(fmax(q, -127.0), 127.0);
  return (char)(int)q;
}

__global__ void k_xquant(const float* __restrict__ x, float* __restrict__ ascale,
                         char* __restrict__ xq, const float4* __restrict__ w4,
                         double* __restrict__ red) {
  const int row = blockIdx.x;
  const int t = threadIdx.x;
  const float4* xr = (const float4*)(x + (size_t)row * K_DIM);
  float4 v0 = xr[t];
  float4 v1 = xr[t + 256];
  float m = fmaxf(fmaxf(fmaxf(fabsf(v0.x), fabsf(v0.y)), fmaxf(fabsf(v0.z), fabsf(v0.w))),
                  fmaxf(fmaxf(fabsf(v1.x), fabsf(v1.y)), fmaxf(fabsf(v1.z), fabsf(v1.w))));
  for (int o = 32; o; o >>= 1) m = fmaxf(m, __shfl_xor(m, o));
  __shared__ float sm[4];
  if ((t & 63) == 0) sm[t >> 6] = m;
  __syncthreads();
  float a = fmaxf(fmaxf(sm[0], sm[1]), fmaxf(sm[2], sm[3]));
  a = fmaxf(a, 1e-8f);
  if (t == 0) ascale[row] = a;
  double rr = 127.0 / (double)a;
  char4* qr4 = (char4*)(xq + (size_t)row * K_DIM);
  char4 a4, b4;
  a4.x = qi8(v0.x, rr); a4.y = qi8(v0.y, rr); a4.z = qi8(v0.z, rr); a4.w = qi8(v0.w, rr);
  b4.x = qi8(v1.x, rr); b4.y = qi8(v1.y, rr); b4.z = qi8(v1.z, rr); b4.w = qi8(v1.w, rr);
  qr4[t] = a4;
  qr4[t + 256] = b4;

  // fused w abs-sum (deterministic partials), blocks 0..255 only
  if (row < 256) {
    const int n4 = NW / 4;
    double s = 0.0;
    for (int i = row * 256 + t; i < n4; i += 256 * 256) {
      float4 v = w4[i];
      s += (double)fabsf(v.x) + (double)fabsf(v.y) + (double)fabsf(v.z) + (double)fabsf(v.w);
    }
    for (int o = 32; o; o >>= 1) s += __shfl_xor(s, o);
    __shared__ double sd[4];
    if ((t & 63) == 0) sd[t >> 6] = s;
    __syncthreads();
    if (t == 0) red[row] = (sd[0] + sd[1]) + (sd[2] + sd[3]);
  }
}

// ---------------- weight ternary quant (wscale folded in) ----------------
__device__ __forceinline__ char wq1(float v, double inv) {
  double r = rint((double)v * inv);         // f64 mul: <=1ulp vs divide, safe
  r = fmin(fmax(r, -1.0), 1.0);
  return (char)(int)r;
}

__global__ void k_wquant(const float4* __restrict__ w4, const double* __restrict__ red,
                         double* __restrict__ wsd, char4* __restrict__ wq4) {
  __shared__ double sd[4];
  double s = red[threadIdx.x];
  for (int o = 32; o; o >>= 1) s += __shfl_xor(s, o);
  if ((threadIdx.x & 63) == 0) sd[threadIdx.x >> 6] = s;
  __syncthreads();
  double m = ((sd[0] + sd[1]) + (sd[2] + sd[3])) / (double)NW;
  double ws = (m > 1e-6) ? m : 1e-6;
  if (blockIdx.x == 0 && threadIdx.x == 0) *wsd = ws;   // for k_gemm epilogue
  double inv = 1.0 / ws;
  int i = blockIdx.x * blockDim.x + threadIdx.x;
  if (i >= NW / 4) return;
  float4 v = w4[i];
  char4 q;
  q.x = wq1(v.x, inv);
  q.y = wq1(v.y, inv);
  q.z = wq1(v.z, inv);
  q.w = wq1(v.w, inv);
  wq4[i] = q;
}

// --- GEMM: 256x256, 8 waves; A via LDS dbuf; B via 1-ktile-ahead reg prefetch
__device__ __forceinline__ void gload16(const void* g, void* l) {
  __builtin_amdgcn_global_load_lds(
      (const __attribute__((address_space(1))) void*)g,
      (__attribute__((address_space(3))) void*)l, 16, 0, 0);
}

#define RD_A(DST, CA, MH, CO)                                               \
  _Pragma("unroll") for (int mf = 0; mf < 4; ++mf)                          \
    DST[mf] = *(const int4v*)((CA) + (rA + (MH)*64 + mf * 16) * 128 + (CO));

#define MM(MH, AF, BF)                                                      \
  __builtin_amdgcn_s_setprio(1);                                            \
  _Pragma("unroll") for (int mf = 0; mf < 4; ++mf)                          \
  _Pragma("unroll") for (int nf = 0; nf < 4; ++nf)                          \
    acc[(MH)*4 + mf][nf] = __builtin_amdgcn_mfma_i32_16x16x64_i8(           \
        AF[mf], BF[nf], acc[(MH)*4 + mf][nf], 0, 0, 0);                     \
  __builtin_amdgcn_s_setprio(0);

// One K-tile:
//  - stage A(kt+1) -> other LDS buf (4 gload_lds, issued FIRST)
//  - prefetch B(kt+1) frags -> spare register set (8 global_load_dwordx4)
//  - compute kt: A frags from LDS, B from current register set
//  - vmcnt(8): retires the 4 A-stage loads (oldest), keeps 8 B-loads flying
//  - one barrier per ktile
#define KTILE(CB, NB, BC0, BC1, BN0, BN1, KT)                               \
  {                                                                         \
    const char* An = Ab + (((KT) + 1) & (NKT - 1)) * BKB;                   \
    const char* Bn = Bb + (((KT) + 1) & (NKT - 1)) * BKB;                   \
    _Pragma("unroll") for (int c = 0; c < 4; ++c)                           \
      gload16(An + soff[c], (NB) + loff[c]);                                \
    _Pragma("unroll") for (int nf = 0; nf < 4; ++nf) {                      \
      BN0[nf] = *(const int4v*)(Bn + sB[nf]);                               \
      BN1[nf] = *(const int4v*)(Bn + sB[nf] + 64);                          \
    }                                                                       \
    RD_A(aX, CB, 0, co0);                                                   \
    RD_A(aY, CB, 1, co0);                                                   \
    MM(0, aX, BC0);                                                         \
    MM(1, aY, BC0);                                                         \
    RD_A(aX, CB, 0, co1);                                                   \
    RD_A(aY, CB, 1, co1);                                                   \
    MM(0, aX, BC1);                                                         \
    MM(1, aY, BC1);                                                         \
    asm volatile("s_waitcnt vmcnt(8)" ::: "memory");                        \
    __builtin_amdgcn_s_barrier();                                           \
  }

__global__ __launch_bounds__(512, 1) void k_gemm(
    const char* __restrict__ xq, const char* __restrict__ wq,
    const float* __restrict__ ascale, const double* __restrict__ wsd,
    float* __restrict__ out) {
  __shared__ __align__(16) char lds[65536];   // 2 x 32 KB A buffers
  char* buf0 = lds;
  char* buf1 = lds + 32768;

  const int tid = threadIdx.x;
  const int l = tid & 63;
  const int wv = tid >> 6;        // 0..7
  const int wm = wv >> 2;         // M half
  const int wn = wv & 3;          // N quarter
  const int g = l >> 4, r16 = l & 15;

  // XCD-aware bijective swizzle: 512 blocks = 8 xcd * 64 chunk
  const int bid = blockIdx.x;
  const int logical = (bid & 7) * 64 + (bid >> 3);
  const int br = logical >> 3;    // 0..63  (M blocks)
  const int bc = logical & 7;     // 0..7   (N blocks)

  const char* Ab = xq + (size_t)br * 256 * K_DIM;
  const char* Bb = wq + (size_t)bc * 256 * K_DIM;

  // A staging: tile = 256 rows x 128 B = 32 KB = 4 chunks (512 thr x 16 B).
  // LDS dest linear (global_load_lds constraint), source pre-swizzled with the
  // proven involution byte ^= (row&7)<<4 (zero conflicts since R2).
  int soff[4], loff[4];
#pragma unroll
  for (int c = 0; c < 4; ++c) {
    int lb = c * 8192 + tid * 16;
    loff[c] = lb;
    int row = lb >> 7;
    int cb = lb & 127;
    soff[c] = row * K_DIM + (cb ^ ((row & 7) << 4));
  }

  // A read-side swizzled column offsets (row&7 == r16&7 for all fragment rows)
  const int sw = (r16 & 7) << 4;
  const int co0 = (g * 16) ^ sw;        // k-slice 0
  const int co1 = (64 + g * 16) ^ sw;   // k-slice 1
  const int rA = wm * 128 + r16;

  // B fragment global byte offsets (R7-validated pattern):
  // row = wn*64 + nf*16 + r16 of the panel, k-byte = g*16 (+ ks*64 + kt*128)
  int sB[4];
#pragma unroll
  for (int nf = 0; nf < 4; ++nf)
    sB[nf] = (wn * 64 + nf * 16 + r16) * K_DIM + g * 16;

  int4v acc[8][4];
#pragma unroll
  for (int mf = 0; mf < 8; ++mf)
#pragma unroll
    for (int nf = 0; nf < 4; ++nf) acc[mf][nf] = (int4v){0, 0, 0, 0};

  // prologue: stage A(0) -> buf0; load B(0) frags into current reg set
#pragma unroll
  for (int c = 0; c < 4; ++c) gload16(Ab + soff[c], buf0 + loff[c]);
  int4v bc0[4], bc1[4], bn0[4], bn1[4];
#pragma unroll
  for (int nf = 0; nf < 4; ++nf) {
    bc0[nf] = *(const int4v*)(Bb + sB[nf]);
    bc1[nf] = *(const int4v*)(Bb + sB[nf] + 64);
  }
  asm volatile("s_waitcnt vmcnt(8)" ::: "memory");  // retire the 4 A-stage loads
  __builtin_amdgcn_s_barrier();

  int4v aX[4], aY[4];

  for (int kt = 0; kt < NKT; kt += 2) {
    KTILE(buf0, buf1, bc0, bc1, bn0, bn1, kt);
    KTILE(buf1, buf0, bn0, bn1, bc0, bc1, kt + 1);
  }

  // epilogue: y = acc * w_scale * (a_scale[t]/127); |acc| <= 127*2048 < 2^24 exact
  float wsf = (float)(*wsd);
  size_t trow0 = (size_t)br * 256 + wm * 128;
  int oc0 = bc * 256 + wn * 64;
#pragma unroll
  for (int mf = 0; mf < 8; ++mf) {
#pragma unroll
    for (int j = 0; j < 4; ++j) {
      size_t t = trow0 + mf * 16 + g * 4 + j;  // C/D: col=lane&15, row=(lane>>4)*4+reg
      float s = wsf * (ascale[t] / 127.0f);
      float* yr = out + t * (size_t)N_DIM + oc0;
#pragma unroll
      for (int nf = 0; nf < 4; ++nf) yr[nf * 16 + r16] = (float)acc[mf][nf][j] * s;
    }
  }
}

extern "C" void kernel_launch(void* const* d_in, const int* in_sizes, int n_in,
                              void* d_out, int out_size, void* d_ws, size_t ws_size,
                              hipStream_t stream) {
  const float* x = (const float*)d_in[0];
  const float* w = (const float*)d_in[1];
  float* out = (float*)d_out;

  char* ws = (char*)d_ws;
  double* red = (double*)ws;                               // 256 * 8 B
  double* wsd = (double*)(ws + 2048);                      // 1 double
  float* ascale = (float*)(ws + 4096);                     // 16384 floats
  char* xq = (char*)(ws + 4096 + 65536);                   // 32 MiB
  char* wq = xq + (size_t)M_DIM * K_DIM;                   // 4 MiB

  k_xquant<<<M_DIM, 256, 0, stream>>>(x, ascale, xq, (const float4*)w, red);
  k_wquant<<<NW / 4 / 256, 256, 0, stream>>>((const float4*)w, red, wsd, (char4*)wq);
  k_gemm<<<dim3(N_DIM / 256 * M_DIM / 256), 512, 0, stream>>>(xq, wq, ascale, wsd, out);
}

// Round 14
// 115.331 us; speedup vs baseline: 1.3481x; 1.3481x over previous
//
#include <hip/hip_runtime.h>
#include <hip/hip_bf16.h>

typedef int int4v __attribute__((ext_vector_type(4)));

#define K_DIM 2048
#define N_DIM 2048
#define M_DIM 16384
#define NW 4194304   // weight element count (2048*2048)
#define BKB 128      // K-step bytes per row (128 i8 elements)
#define NKT (K_DIM / BKB)   // 16 K-tiles

// ------------- fused: per-token absmax+quant (f32, matches ref), wsum slice --
__device__ __forceinline__ char qi8f(float v, float rr) {
  float q = rintf(v * rr);                   // f32 mul+round = reference path
  q = fminf(fmaxf(q, -127.0f), 127.0f);
  return (char)(int)q;
}

__global__ void k_xquant(const float* __restrict__ x, float* __restrict__ ascale,
                         char* __restrict__ xq, const float4* __restrict__ w4,
                         double* __restrict__ red) {
  const int row = blockIdx.x;
  const int t = threadIdx.x;
  const float4* xr = (const float4*)(x + (size_t)row * K_DIM);
  float4 v0 = xr[t];
  float4 v1 = xr[t + 256];
  float m = fmaxf(fmaxf(fmaxf(fabsf(v0.x), fabsf(v0.y)), fmaxf(fabsf(v0.z), fabsf(v0.w))),
                  fmaxf(fmaxf(fabsf(v1.x), fabsf(v1.y)), fmaxf(fabsf(v1.z), fabsf(v1.w))));
  for (int o = 32; o; o >>= 1) m = fmaxf(m, __shfl_xor(m, o));
  __shared__ float sm[4];
  if ((t & 63) == 0) sm[t >> 6] = m;
  __syncthreads();
  float a = fmaxf(fmaxf(sm[0], sm[1]), fmaxf(sm[2], sm[3]));
  a = fmaxf(a, 1e-8f);
  if (t == 0) ascale[row] = a;
  float rr = 127.0f / a;                     // f32, exactly as reference
  char4* qr4 = (char4*)(xq + (size_t)row * K_DIM);
  char4 a4, b4;
  a4.x = qi8f(v0.x, rr); a4.y = qi8f(v0.y, rr); a4.z = qi8f(v0.z, rr); a4.w = qi8f(v0.w, rr);
  b4.x = qi8f(v1.x, rr); b4.y = qi8f(v1.y, rr); b4.z = qi8f(v1.z, rr); b4.w = qi8f(v1.w, rr);
  qr4[t] = a4;
  qr4[t + 256] = b4;

  // fused w abs-sum (deterministic partials), blocks 0..255 only
  if (row < 256) {
    const int n4 = NW / 4;
    double s = 0.0;
    for (int i = row * 256 + t; i < n4; i += 256 * 256) {
      float4 v = w4[i];
      s += (double)fabsf(v.x) + (double)fabsf(v.y) + (double)fabsf(v.z) + (double)fabsf(v.w);
    }
    for (int o = 32; o; o >>= 1) s += __shfl_xor(s, o);
    __shared__ double sd[4];
    if ((t & 63) == 0) sd[t >> 6] = s;
    __syncthreads();
    if (t == 0) red[row] = (sd[0] + sd[1]) + (sd[2] + sd[3]);
  }
}

// ---------------- weight ternary quant (f32 math, wscale folded in) ----------
__device__ __forceinline__ char wq1f(float v, float inv) {
  float r = rintf(v * inv);                  // f32, <=1ulp vs f32-divide
  r = fminf(fmaxf(r, -1.0f), 1.0f);
  return (char)(int)r;
}

__global__ void k_wquant(const float4* __restrict__ w4, const double* __restrict__ red,
                         double* __restrict__ wsd, char4* __restrict__ wq4) {
  __shared__ double sd[4];
  double s = red[threadIdx.x];
  for (int o = 32; o; o >>= 1) s += __shfl_xor(s, o);
  if ((threadIdx.x & 63) == 0) sd[threadIdx.x >> 6] = s;
  __syncthreads();
  double m = ((sd[0] + sd[1]) + (sd[2] + sd[3])) / (double)NW;
  double ws = (m > 1e-6) ? m : 1e-6;
  if (blockIdx.x == 0 && threadIdx.x == 0) *wsd = ws;   // for k_gemm epilogue
  float inv = (float)(1.0 / ws);
  int i = blockIdx.x * blockDim.x + threadIdx.x;
  if (i >= NW / 4) return;
  float4 v = w4[i];
  char4 q;
  q.x = wq1f(v.x, inv);
  q.y = wq1f(v.y, inv);
  q.z = wq1f(v.z, inv);
  q.w = wq1f(v.w, inv);
  wq4[i] = q;
}

// --- GEMM: R11 verbatim (best: 75.2us, MfmaUtil 36.6%, 0 conflicts) ---------
__device__ __forceinline__ void gload16(const void* g, void* l) {
  __builtin_amdgcn_global_load_lds(
      (const __attribute__((address_space(1))) void*)g,
      (__attribute__((address_space(3))) void*)l, 16, 0, 0);
}

#define RD_A(DST, CA, MH, CO)                                               \
  _Pragma("unroll") for (int mf = 0; mf < 4; ++mf)                          \
    DST[mf] = *(const int4v*)((CA) + (rA + (MH)*64 + mf * 16) * 128 + (CO));

#define RD_B(DST, CB, CO)                                                   \
  _Pragma("unroll") for (int nf = 0; nf < 4; ++nf)                          \
    DST[nf] = *(const int4v*)((CB) + (rB + nf * 16) * 128 + (CO));

#define MM(MH, AF, BF)                                                      \
  __builtin_amdgcn_s_setprio(1);                                            \
  _Pragma("unroll") for (int mf = 0; mf < 4; ++mf)                          \
  _Pragma("unroll") for (int nf = 0; nf < 4; ++nf)                          \
    acc[(MH)*4 + mf][nf] = __builtin_amdgcn_mfma_i32_16x16x64_i8(           \
        AF[mf], BF[nf], acc[(MH)*4 + mf][nf], 0, 0, 0);                     \
  __builtin_amdgcn_s_setprio(0);

#define KTILE(CB, NB, KT)                                                   \
  {                                                                         \
    const char* An = Ab + (((KT) + 1) & (NKT - 1)) * BKB;                   \
    const char* Bn = Bb + (((KT) + 1) & (NKT - 1)) * BKB;                   \
    _Pragma("unroll") for (int c = 0; c < 4; ++c)                           \
      gload16(An + soff[c], (NB) + loff[c]);                                \
    _Pragma("unroll") for (int c = 0; c < 4; ++c)                           \
      gload16(Bn + soff[c], (NB) + 32768 + loff[c]);                        \
    RD_A(aX, CB, 0, co0);                                                   \
    RD_B(bX, (CB) + 32768, co0);                                            \
    RD_A(aY, CB, 1, co0);                                                   \
    MM(0, aX, bX);                                                          \
    RD_B(bY, (CB) + 32768, co1);                                            \
    MM(1, aY, bX);                                                          \
    RD_A(aX, CB, 0, co1);                                                   \
    MM(0, aX, bY);                                                          \
    RD_A(aY, CB, 1, co1);                                                   \
    MM(1, aY, bY);                                                          \
    asm volatile("s_waitcnt vmcnt(0)" ::: "memory");                        \
    __builtin_amdgcn_s_barrier();                                           \
  }

__global__ __launch_bounds__(512, 1) void k_gemm(
    const char* __restrict__ xq, const char* __restrict__ wq,
    const float* __restrict__ ascale, const double* __restrict__ wsd,
    float* __restrict__ out) {
  __shared__ __align__(16) char lds[131072];   // 2 bufs x (A 32K | B 32K)
  char* buf0 = lds;
  char* buf1 = lds + 65536;

  const int tid = threadIdx.x;
  const int l = tid & 63;
  const int wv = tid >> 6;        // 0..7
  const int wm = wv >> 2;         // M half
  const int wn = wv & 3;          // N quarter
  const int g = l >> 4, r16 = l & 15;

  // XCD-aware bijective swizzle: 512 blocks = 8 xcd * 64 chunk
  const int bid = blockIdx.x;
  const int logical = (bid & 7) * 64 + (bid >> 3);
  const int br = logical >> 3;    // 0..63  (M blocks)
  const int bc = logical & 7;     // 0..7   (N blocks)

  const char* Ab = xq + (size_t)br * 256 * K_DIM;
  const char* Bb = wq + (size_t)bc * 256 * K_DIM;

  // staging: operand tile = 256 rows x 128 B = 32 KB = 4 chunks (512 thr x 16 B)
  // LDS dest linear (global_load_lds constraint), source pre-swizzled with the
  // proven involution byte ^= (row&7)<<4 (128 B rows, 0 conflicts R2-R13)
  int soff[4], loff[4];
#pragma unroll
  for (int c = 0; c < 4; ++c) {
    int lb = c * 8192 + tid * 16;
    loff[c] = lb;
    int row = lb >> 7;
    int cb = lb & 127;
    soff[c] = row * K_DIM + (cb ^ ((row & 7) << 4));
  }

  // read-side swizzled column offsets (row&7 == r16&7 for all fragment rows)
  const int sw = (r16 & 7) << 4;
  const int co0 = (g * 16) ^ sw;        // k-slice 0
  const int co1 = (64 + g * 16) ^ sw;   // k-slice 1
  const int rA = wm * 128 + r16;
  const int rB = wn * 64 + r16;

  int4v acc[8][4];
#pragma unroll
  for (int mf = 0; mf < 8; ++mf)
#pragma unroll
    for (int nf = 0; nf < 4; ++nf) acc[mf][nf] = (int4v){0, 0, 0, 0};

  // prologue: stage tile 0 into buf0, drain, sync
#pragma unroll
  for (int c = 0; c < 4; ++c) gload16(Ab + soff[c], buf0 + loff[c]);
#pragma unroll
  for (int c = 0; c < 4; ++c) gload16(Bb + soff[c], buf0 + 32768 + loff[c]);
  asm volatile("s_waitcnt vmcnt(0)" ::: "memory");
  __builtin_amdgcn_s_barrier();

  int4v aX[4], aY[4], bX[4], bY[4];

  for (int kt = 0; kt < NKT; kt += 2) {
    KTILE(buf0, buf1, kt);
    KTILE(buf1, buf0, kt + 1);
  }

  // epilogue: y = acc * w_scale * (a_scale[t]/127); |acc| <= 127*2048 < 2^24 exact
  float wsf = (float)(*wsd);
  size_t trow0 = (size_t)br * 256 + wm * 128;
  int oc0 = bc * 256 + wn * 64;
#pragma unroll
  for (int mf = 0; mf < 8; ++mf) {
#pragma unroll
    for (int j = 0; j < 4; ++j) {
      size_t t = trow0 + mf * 16 + g * 4 + j;  // C/D: col=lane&15, row=(lane>>4)*4+reg
      float s = wsf * (ascale[t] / 127.0f);
      float* yr = out + t * (size_t)N_DIM + oc0;
#pragma unroll
      for (int nf = 0; nf < 4; ++nf) yr[nf * 16 + r16] = (float)acc[mf][nf][j] * s;
    }
  }
}

extern "C" void kernel_launch(void* const* d_in, const int* in_sizes, int n_in,
                              void* d_out, int out_size, void* d_ws, size_t ws_size,
                              hipStream_t stream) {
  const float* x = (const float*)d_in[0];
  const float* w = (const float*)d_in[1];
  float* out = (float*)d_out;

  char* ws = (char*)d_ws;
  double* red = (double*)ws;                               // 256 * 8 B
  double* wsd = (double*)(ws + 2048);                      // 1 double
  float* ascale = (float*)(ws + 4096);                     // 16384 floats
  char* xq = (char*)(ws + 4096 + 65536);                   // 32 MiB
  char* wq = xq + (size_t)M_DIM * K_DIM;                   // 4 MiB

  k_xquant<<<M_DIM, 256, 0, stream>>>(x, ascale, xq, (const float4*)w, red);
  k_wquant<<<NW / 4 / 256, 256, 0, stream>>>((const float4*)w, red, wsd, (char4*)wq);
  k_gemm<<<dim3(N_DIM / 256 * M_DIM / 256), 512, 0, stream>>>(xq, wq, ascale, wsd, out);
}